// Round 1
// baseline (393.858 us; speedup 1.0000x reference)
//
#include <hip/hip_runtime.h>
#include <hip/hip_bf16.h>

// Problem constants (fixed by setup_inputs): B=8, H=W=64, T=4096, C=256
#define TB 8
#define TT 4096
#define TC 256
#define NCH 64   // chunks along T
#define CL 64    // chunk length

// ---------------- GEMM: C[m,n] = sum_k A[m,k] * W[n,k]  (x @ W^T) -------------
// M=32768, K=256, each W is 256x256. grid.y selects (W, 128-col block).
#define BM 128
#define BN 128
#define BKK 8

__global__ __launch_bounds__(256) void gemm_nt(
    const float* __restrict__ A,
    const float* __restrict__ W0, const float* __restrict__ W1, const float* __restrict__ W2,
    float* __restrict__ C0, float* __restrict__ C1, float* __restrict__ C2,
    int sigmoid_mask)
{
    const int K = TC;
    int by = blockIdx.y;
    int wsel = by >> 1;
    const float* W = (wsel == 0) ? W0 : (wsel == 1) ? W1 : W2;
    float* Cc      = (wsel == 0) ? C0 : (wsel == 1) ? C1 : C2;
    int col0 = (by & 1) * BN;
    int row0 = blockIdx.x * BM;
    int sig = (sigmoid_mask >> wsel) & 1;

    __shared__ float As[BKK][BM];
    __shared__ float Bs[BKK][BN];

    int tid = threadIdx.x;
    int tx = tid & 15;   // n microtile
    int ty = tid >> 4;   // m microtile

    int lm  = tid >> 1;        // 0..127 staging row
    int lk4 = (tid & 1) * 4;   // 0 or 4 staging k-offset

    float acc[8][8];
    #pragma unroll
    for (int i = 0; i < 8; i++)
        #pragma unroll
        for (int jj = 0; jj < 8; jj++) acc[i][jj] = 0.f;

    const float* Aptr = A + (size_t)(row0 + lm) * K + lk4;
    const float* Wptr = W + (size_t)(col0 + lm) * K + lk4;

    for (int kb = 0; kb < K; kb += BKK) {
        float4 av = *(const float4*)(Aptr + kb);
        float4 bv = *(const float4*)(Wptr + kb);
        __syncthreads();
        As[lk4 + 0][lm] = av.x; As[lk4 + 1][lm] = av.y;
        As[lk4 + 2][lm] = av.z; As[lk4 + 3][lm] = av.w;
        Bs[lk4 + 0][lm] = bv.x; Bs[lk4 + 1][lm] = bv.y;
        Bs[lk4 + 2][lm] = bv.z; Bs[lk4 + 3][lm] = bv.w;
        __syncthreads();
        #pragma unroll
        for (int kk = 0; kk < BKK; kk++) {
            float4 a0 = *(const float4*)&As[kk][ty * 8];
            float4 a1 = *(const float4*)&As[kk][ty * 8 + 4];
            float4 b0 = *(const float4*)&Bs[kk][tx * 8];
            float4 b1 = *(const float4*)&Bs[kk][tx * 8 + 4];
            float a[8] = {a0.x, a0.y, a0.z, a0.w, a1.x, a1.y, a1.z, a1.w};
            float b[8] = {b0.x, b0.y, b0.z, b0.w, b1.x, b1.y, b1.z, b1.w};
            #pragma unroll
            for (int i = 0; i < 8; i++)
                #pragma unroll
                for (int jj = 0; jj < 8; jj++)
                    acc[i][jj] = fmaf(a[i], b[jj], acc[i][jj]);
        }
    }

    #pragma unroll
    for (int i = 0; i < 8; i++) {
        int m = row0 + ty * 8 + i;
        float* crow = Cc + (size_t)m * TC + col0 + tx * 8;
        if (sig) {
            #pragma unroll
            for (int jj = 0; jj < 8; jj++)
                acc[i][jj] = 1.f / (1.f + __expf(-acc[i][jj]));
        }
        float4 o0 = make_float4(acc[i][0], acc[i][1], acc[i][2], acc[i][3]);
        float4 o1 = make_float4(acc[i][4], acc[i][5], acc[i][6], acc[i][7]);
        *(float4*)(crow)     = o0;
        *(float4*)(crow + 4) = o1;
    }
}

// ---------------- Sobel edge gate: edge[b,t] = sigmoid(mean_c |grad|) --------
__global__ __launch_bounds__(256) void sobel_edge(
    const float* __restrict__ x, float* __restrict__ edge)
{
    int t = blockIdx.x & (TT - 1);
    int b = blockIdx.x >> 12;
    int h = t >> 6, w = t & 63;
    int c = threadIdx.x;

    float n[3][3];
    #pragma unroll
    for (int dh = 0; dh < 3; dh++) {
        int hh = h + dh - 1;
        #pragma unroll
        for (int dw = 0; dw < 3; dw++) {
            int ww = w + dw - 1;
            float val = 0.f;
            if (hh >= 0 && hh < 64 && ww >= 0 && ww < 64)
                val = x[((size_t)(b * TT + (hh << 6) + ww)) * TC + c];
            n[dh][dw] = val;
        }
    }
    float gx = (n[0][2] - n[0][0]) + 2.f * (n[1][2] - n[1][0]) + (n[2][2] - n[2][0]);
    float gy = (n[2][0] + 2.f * n[2][1] + n[2][2]) - (n[0][0] + 2.f * n[0][1] + n[0][2]);
    float mag = sqrtf(gx * gx + gy * gy + 1e-8f);

    #pragma unroll
    for (int off = 32; off > 0; off >>= 1) mag += __shfl_down(mag, off, 64);
    __shared__ float part[4];
    if ((threadIdx.x & 63) == 0) part[threadIdx.x >> 6] = mag;
    __syncthreads();
    if (threadIdx.x == 0) {
        float s = part[0] + part[1] + part[2] + part[3];
        float mean = s * (1.f / 256.f);
        edge[blockIdx.x] = 1.f / (1.f + __expf(-mean));
    }
}

// ---------------- WKV phase A: per-chunk local sums (both directions) --------
// fwd end-state:  Sa = sum_i d^(63-i) e^{k_i} v_i   (i ascending in chunk)
// bwd start-state: Ra = sum_i d^i e^{k_i} v_i
__global__ __launch_bounds__(256) void wkv_chunk_sums(
    const float* __restrict__ kp, const float* __restrict__ vp,
    const float* __restrict__ decay,
    float* __restrict__ SaF, float* __restrict__ SbF,
    float* __restrict__ RaB, float* __restrict__ RbB)
{
    int tid = blockIdx.x * 256 + threadIdx.x;   // B*NCH*C
    int c = tid & 255;
    int j = (tid >> 8) & (NCH - 1);
    int b = tid >> 14;
    float w = decay[c] * (1.f / (float)TT);
    float d = __expf(-w);
    size_t base = ((size_t)(b * TT + j * CL)) * TC + c;
    float Sa = 0.f, Sb = 0.f, Ra = 0.f, Rb = 0.f, pw = 1.f;
    for (int i = 0; i < CL; i++) {
        float kk = kp[base + (size_t)i * TC];
        float vv = vp[base + (size_t)i * TC];
        float ek = __expf(kk);
        float ekv = ek * vv;
        Sa = fmaf(d, Sa, ekv);
        Sb = fmaf(d, Sb, ek);
        Ra = fmaf(pw, ekv, Ra);
        Rb = fmaf(pw, ek, Rb);
        pw *= d;
    }
    int idx = (b * NCH + j) * TC + c;
    SaF[idx] = Sa; SbF[idx] = Sb; RaB[idx] = Ra; RbB[idx] = Rb;
}

// ---------------- WKV phase B: scan chunk sums -> per-chunk carries ----------
__global__ __launch_bounds__(256) void wkv_carries(
    const float* __restrict__ SaF, const float* __restrict__ SbF,
    const float* __restrict__ RaB, const float* __restrict__ RbB,
    const float* __restrict__ decay,
    float* __restrict__ CfA, float* __restrict__ CfB,
    float* __restrict__ CbA, float* __restrict__ CbB)
{
    int tid = blockIdx.x * 256 + threadIdx.x;  // B*C = 2048
    int c = tid & 255;
    int b = tid >> 8;
    float w = decay[c] * (1.f / (float)TT);
    float D = __expf(-(float)CL * w);
    float cfa = 0.f, cfb = 0.f;
    for (int j = 0; j < NCH; j++) {
        int idx = (b * NCH + j) * TC + c;
        CfA[idx] = cfa; CfB[idx] = cfb;
        cfa = fmaf(D, cfa, SaF[idx]);
        cfb = fmaf(D, cfb, SbF[idx]);
    }
    float cba = 0.f, cbb = 0.f;
    for (int j = NCH - 1; j >= 0; j--) {
        int idx = (b * NCH + j) * TC + c;
        CbA[idx] = cba; CbB[idx] = cbb;
        cba = fmaf(D, cba, RaB[idx]);
        cbb = fmaf(D, cbb, RbB[idx]);
    }
}

// ---------------- WKV phase C: rebuild prefixes, combine, gate ---------------
// block = 64 threads (one c-quarter), handles one (b, chunk). Bwd prefix for
// the chunk kept in a private LDS column per thread (no cross-thread sharing).
__global__ __launch_bounds__(64) void wkv_combine(
    const float* __restrict__ kp, const float* __restrict__ vp,
    const float* __restrict__ srp, const float* __restrict__ edgep,
    const float* __restrict__ decay, const float* __restrict__ first,
    const float* __restrict__ CfA, const float* __restrict__ CfB,
    const float* __restrict__ CbA, const float* __restrict__ CbB,
    float* __restrict__ y)
{
    __shared__ float abL[CL][64];
    __shared__ float bbL[CL][64];
    int bid = blockIdx.x;            // B*NCH*4
    int cg = bid & 3;
    int j = (bid >> 2) & (NCH - 1);
    int b = bid >> 8;
    int lane = threadIdx.x;
    int c = cg * 64 + lane;

    float w = decay[c] * (1.f / (float)TT);
    float d = __expf(-w);
    float eu = __expf(first[c] * (1.f / (float)TT));
    int cidx = (b * NCH + j) * TC + c;
    size_t base = ((size_t)(b * TT + j * CL)) * TC + c;

    // descending pass: backward prefix Ab_t (state over s>t), stash in LDS
    float ab = CbA[cidx], bb = CbB[cidx];
    for (int i = CL - 1; i >= 0; i--) {
        float kk = kp[base + (size_t)i * TC];
        float vv = vp[base + (size_t)i * TC];
        float ek = __expf(kk);
        abL[i][lane] = ab; bbL[i][lane] = bb;
        ab = fmaf(d, ab, ek * vv);
        bb = fmaf(d, bb, ek);
    }
    // ascending pass: forward prefix + combine + gate
    float af = CfA[cidx], bf = CfB[cidx];
    for (int i = 0; i < CL; i++) {
        size_t idx = base + (size_t)i * TC;
        float kk = kp[idx];
        float vv = vp[idx];
        float srv = srp[idx];
        float ek = __expf(kk);
        float es = ek * eu;                 // e^{u + k_t}
        float num = af + abL[i][lane] + es * vv;
        float den = bf + bbL[i][lane] + es;
        float ev = edgep[b * TT + j * CL + i];
        y[idx] = (srv + ev) * (num / den);
        af = fmaf(d, af, ek * vv);
        bf = fmaf(d, bf, ek);
    }
}

// -----------------------------------------------------------------------------
extern "C" void kernel_launch(void* const* d_in, const int* in_sizes, int n_in,
                              void* d_out, int out_size, void* d_ws, size_t ws_size,
                              hipStream_t stream)
{
    const float* x      = (const float*)d_in[0];
    const float* Wk     = (const float*)d_in[1];
    const float* Wv     = (const float*)d_in[2];
    const float* Wr     = (const float*)d_in[3];
    const float* Wo     = (const float*)d_in[4];
    const float* sdecay = (const float*)d_in[5];
    const float* sfirst = (const float*)d_in[6];
    float* out = (float*)d_out;

    char* ws = (char*)d_ws;
    size_t off = 0;
    const size_t MB32 = (size_t)TB * TT * TC * sizeof(float);   // 32 MB
    float* kbuf  = (float*)(ws + off); off += MB32;
    float* vbuf  = (float*)(ws + off); off += MB32;
    float* srbuf = (float*)(ws + off); off += MB32;
    float* ybuf  = (float*)(ws + off); off += MB32;
    float* edge  = (float*)(ws + off); off += (size_t)TB * TT * sizeof(float);
    const size_t CHB = (size_t)TB * NCH * TC * sizeof(float);   // 512 KB each
    float* SaF = (float*)(ws + off); off += CHB;
    float* SbF = (float*)(ws + off); off += CHB;
    float* RaB = (float*)(ws + off); off += CHB;
    float* RbB = (float*)(ws + off); off += CHB;
    float* CfA = (float*)(ws + off); off += CHB;
    float* CfB = (float*)(ws + off); off += CHB;
    float* CbA = (float*)(ws + off); off += CHB;
    float* CbB = (float*)(ws + off); off += CHB;

    const int MBLK = (TB * TT) / BM;   // 256

    // 1) k, v, sr=sigmoid(r)
    gemm_nt<<<dim3(MBLK, 6), 256, 0, stream>>>(x, Wk, Wv, Wr, kbuf, vbuf, srbuf, 4);
    // 2) edge gate (independent of GEMM)
    sobel_edge<<<TB * TT, 256, 0, stream>>>(x, edge);
    // 3) chunk-local scan sums
    wkv_chunk_sums<<<(TB * NCH * TC) / 256, 256, 0, stream>>>(kbuf, vbuf, sdecay,
                                                              SaF, SbF, RaB, RbB);
    // 4) carries across chunks
    wkv_carries<<<(TB * TC) / 256, 256, 0, stream>>>(SaF, SbF, RaB, RbB, sdecay,
                                                     CfA, CfB, CbA, CbB);
    // 5) combine + gate -> y
    wkv_combine<<<TB * NCH * 4, 64, 0, stream>>>(kbuf, vbuf, srbuf, edge,
                                                 sdecay, sfirst,
                                                 CfA, CfB, CbA, CbB, ybuf);
    // 6) out = y @ Wo^T
    gemm_nt<<<dim3(MBLK, 2), 256, 0, stream>>>(ybuf, Wo, Wo, Wo, out, out, out, 0);
}

// Round 2
// 247.582 us; speedup vs baseline: 1.5908x; 1.5908x over previous
//
#include <hip/hip_runtime.h>
#include <hip/hip_bf16.h>

// Problem constants: B=8, H=W=64, T=4096, C=256
#define TB 8
#define TT 4096
#define TC 256
#define NC2 128   // chunks along T
#define CL2 32    // chunk length

#define K2 512    // f16 split K (2x256)
#define BM 128
#define BN 128
#define BK 32

typedef _Float16 half8 __attribute__((ext_vector_type(8)));
typedef _Float16 half2v __attribute__((ext_vector_type(2)));
typedef float floatx4 __attribute__((ext_vector_type(4)));

#define GLDS16(g, l) __builtin_amdgcn_global_load_lds( \
    (const __attribute__((address_space(1))) void*)(g), \
    (__attribute__((address_space(3))) void*)(l), 16, 0, 0)

// ---------------- input split: X2[m][2k]=fp16(x), X2[m][2k+1]=fp16(x-hi) ----
__global__ __launch_bounds__(256) void convert_x(
    const float* __restrict__ x, _Float16* __restrict__ X2, int n4)
{
    int t = blockIdx.x * 256 + threadIdx.x;
    if (t >= n4) return;
    float4 xv = ((const float4*)x)[t];
    half8 o;
    o[0] = (_Float16)xv.x; o[1] = (_Float16)(xv.x - (float)o[0]);
    o[2] = (_Float16)xv.y; o[3] = (_Float16)(xv.y - (float)o[2]);
    o[4] = (_Float16)xv.z; o[5] = (_Float16)(xv.z - (float)o[4]);
    o[6] = (_Float16)xv.w; o[7] = (_Float16)(xv.w - (float)o[6]);
    ((half8*)X2)[t] = o;
}

// ---------------- weight duplicate: W2[n][2k]=W2[n][2k+1]=fp16(W[n][k]) -----
__global__ __launch_bounds__(256) void convert_w(
    const float* __restrict__ Wk, const float* __restrict__ Wv,
    const float* __restrict__ Wr, const float* __restrict__ Wo,
    _Float16* __restrict__ W2, _Float16* __restrict__ Wo2)
{
    int t = blockIdx.x * 256 + threadIdx.x;     // 4 * 65536
    int wsel = t >> 16;
    int i = t & 65535;
    const float* src = (wsel == 0) ? Wk : (wsel == 1) ? Wv : (wsel == 2) ? Wr : Wo;
    _Float16* dst = (wsel < 3) ? (W2 + (size_t)wsel * TC * K2) : Wo2;
    _Float16 h = (_Float16)src[i];
    half2v p; p.x = h; p.y = h;
    *(half2v*)(dst + 2 * (size_t)i) = p;
}

// ---------------- MFMA GEMM: C[m,n] = A2[m,:] . W2[n,:]  (K'=512) -----------
// 128x128 tile, 4 waves, each wave a 64x64 quadrant of 4x4 16x16x32 MFMAs.
__global__ __launch_bounds__(256) void gemm_f16(
    const _Float16* __restrict__ A2,
    const _Float16* __restrict__ W0, const _Float16* __restrict__ W1,
    const _Float16* __restrict__ W2p,
    float* __restrict__ C0, float* __restrict__ C1, float* __restrict__ C2,
    int sigmoid_mask)
{
    __shared__ _Float16 As[BM * BK];   // 8KB, row-major [128][32]
    __shared__ _Float16 Bs[BN * BK];   // 8KB

    int by = blockIdx.y;
    int wsel = by >> 1;
    const _Float16* W = (wsel == 0) ? W0 : (wsel == 1) ? W1 : W2p;
    float* Cc         = (wsel == 0) ? C0 : (wsel == 1) ? C1 : C2;
    int col0 = (by & 1) * BN;
    int row0 = blockIdx.x * BM;
    int sig = (sigmoid_mask >> wsel) & 1;

    int tid = threadIdx.x;
    int lane = tid & 63;
    int wv = tid >> 6;
    int qm = (wv >> 1) * 64;
    int qn = (wv & 1) * 64;
    int mrow = lane & 15;
    int kgrp = (lane >> 4) * 8;

    const _Float16* Ag = A2 + (size_t)row0 * K2;
    const _Float16* Bg = W + (size_t)col0 * K2;

    floatx4 acc[4][4];
    #pragma unroll
    for (int i = 0; i < 4; i++)
        #pragma unroll
        for (int j = 0; j < 4; j++)
            acc[i][j] = (floatx4){0.f, 0.f, 0.f, 0.f};

    for (int kb = 0; kb < K2; kb += BK) {
        __syncthreads();
        #pragma unroll
        for (int r = 0; r < 2; r++) {
            int seg = r * 256 + tid;            // 16B segment index
            int row = seg >> 2;
            int ks = (seg & 3) * 8;
            GLDS16(Ag + (size_t)row * K2 + kb + ks, &As[seg * 8]);
            GLDS16(Bg + (size_t)row * K2 + kb + ks, &Bs[seg * 8]);
        }
        __syncthreads();
        half8 a[4], b[4];
        #pragma unroll
        for (int i = 0; i < 4; i++)
            a[i] = *(const half8*)&As[(qm + i * 16 + mrow) * BK + kgrp];
        #pragma unroll
        for (int j = 0; j < 4; j++)
            b[j] = *(const half8*)&Bs[(qn + j * 16 + mrow) * BK + kgrp];
        #pragma unroll
        for (int i = 0; i < 4; i++)
            #pragma unroll
            for (int j = 0; j < 4; j++)
                acc[i][j] = __builtin_amdgcn_mfma_f32_16x16x32_f16(
                    a[i], b[j], acc[i][j], 0, 0, 0);
    }

    // D mapping (16x16): row m = (lane>>4)*4 + reg, col n = lane&15
    int mr0 = (lane >> 4) * 4;
    int nc = lane & 15;
    #pragma unroll
    for (int i = 0; i < 4; i++) {
        #pragma unroll
        for (int r = 0; r < 4; r++) {
            int m = row0 + qm + i * 16 + mr0 + r;
            float* crow = Cc + (size_t)m * TC + col0 + qn;
            #pragma unroll
            for (int j = 0; j < 4; j++) {
                float vvv = acc[i][j][r];
                if (sig) vvv = 1.f / (1.f + __expf(-vvv));
                crow[j * 16 + nc] = vvv;
            }
        }
    }
}

// ---------------- Sobel edge gate --------------------------------------------
__global__ __launch_bounds__(256) void sobel_edge(
    const float* __restrict__ x, float* __restrict__ edge)
{
    int t = blockIdx.x & (TT - 1);
    int b = blockIdx.x >> 12;
    int h = t >> 6, w = t & 63;
    int c = threadIdx.x;

    float n[3][3];
    #pragma unroll
    for (int dh = 0; dh < 3; dh++) {
        int hh = h + dh - 1;
        #pragma unroll
        for (int dw = 0; dw < 3; dw++) {
            int ww = w + dw - 1;
            float val = 0.f;
            if (hh >= 0 && hh < 64 && ww >= 0 && ww < 64)
                val = x[((size_t)(b * TT + (hh << 6) + ww)) * TC + c];
            n[dh][dw] = val;
        }
    }
    float gx = (n[0][2] - n[0][0]) + 2.f * (n[1][2] - n[1][0]) + (n[2][2] - n[2][0]);
    float gy = (n[2][0] + 2.f * n[2][1] + n[2][2]) - (n[0][0] + 2.f * n[0][1] + n[0][2]);
    float mag = sqrtf(gx * gx + gy * gy + 1e-8f);

    #pragma unroll
    for (int off = 32; off > 0; off >>= 1) mag += __shfl_down(mag, off, 64);
    __shared__ float part[4];
    if ((threadIdx.x & 63) == 0) part[threadIdx.x >> 6] = mag;
    __syncthreads();
    if (threadIdx.x == 0) {
        float s = part[0] + part[1] + part[2] + part[3];
        edge[blockIdx.x] = 1.f / (1.f + __expf(-s * (1.f / 256.f)));
    }
}

// ---------------- WKV phase A: per-chunk local sums --------------------------
__global__ __launch_bounds__(256) void wkv_chunk_sums(
    const float* __restrict__ kp, const float* __restrict__ vp,
    const float* __restrict__ decay,
    float* __restrict__ SaF, float* __restrict__ SbF,
    float* __restrict__ RaB, float* __restrict__ RbB)
{
    int tid = blockIdx.x * 256 + threadIdx.x;   // B*NC2*C
    int c = tid & 255;
    int j = (tid >> 8) & (NC2 - 1);
    int b = tid >> 15;
    float w = decay[c] * (1.f / (float)TT);
    float d = __expf(-w);
    size_t base = ((size_t)(b * TT + j * CL2)) * TC + c;
    float Sa = 0.f, Sb = 0.f, Ra = 0.f, Rb = 0.f, pw = 1.f;
    #pragma unroll
    for (int i = 0; i < CL2; i++) {
        float kk = kp[base + (size_t)i * TC];
        float vv = vp[base + (size_t)i * TC];
        float ek = __expf(kk);
        float ekv = ek * vv;
        Sa = fmaf(d, Sa, ekv);
        Sb = fmaf(d, Sb, ek);
        Ra = fmaf(pw, ekv, Ra);
        Rb = fmaf(pw, ek, Rb);
        pw *= d;
    }
    int idx = (b * NC2 + j) * TC + c;
    SaF[idx] = Sa; SbF[idx] = Sb; RaB[idx] = Ra; RbB[idx] = Rb;
}

// ---------------- WKV phase B: chunk carries ---------------------------------
__global__ __launch_bounds__(256) void wkv_carries(
    const float* __restrict__ SaF, const float* __restrict__ SbF,
    const float* __restrict__ RaB, const float* __restrict__ RbB,
    const float* __restrict__ decay,
    float* __restrict__ CfA, float* __restrict__ CfB,
    float* __restrict__ CbA, float* __restrict__ CbB)
{
    int tid = blockIdx.x * 256 + threadIdx.x;  // B*C = 2048
    int c = tid & 255;
    int b = tid >> 8;
    float w = decay[c] * (1.f / (float)TT);
    float D = __expf(-(float)CL2 * w);
    float cfa = 0.f, cfb = 0.f;
    for (int j = 0; j < NC2; j++) {
        int idx = (b * NC2 + j) * TC + c;
        CfA[idx] = cfa; CfB[idx] = cfb;
        cfa = fmaf(D, cfa, SaF[idx]);
        cfb = fmaf(D, cfb, SbF[idx]);
    }
    float cba = 0.f, cbb = 0.f;
    for (int j = NC2 - 1; j >= 0; j--) {
        int idx = (b * NC2 + j) * TC + c;
        CbA[idx] = cba; CbB[idx] = cbb;
        cba = fmaf(D, cba, RaB[idx]);
        cbb = fmaf(D, cbb, RbB[idx]);
    }
}

// ---------------- WKV phase C: combine + gate -> Y2 (f16 hi/lo pairs) -------
// 256 threads = all c for one (b, chunk). Backward prefix in 64 unrolled regs.
__global__ __launch_bounds__(256) void wkv_combine(
    const float* __restrict__ kp, const float* __restrict__ vp,
    const float* __restrict__ srp, const float* __restrict__ edgep,
    const float* __restrict__ decay, const float* __restrict__ first,
    const float* __restrict__ CfA, const float* __restrict__ CfB,
    const float* __restrict__ CbA, const float* __restrict__ CbB,
    _Float16* __restrict__ Y2)
{
    int bid = blockIdx.x;            // B*NC2 = 1024
    int j = bid & (NC2 - 1);
    int b = bid >> 7;
    int c = threadIdx.x;

    float w = decay[c] * (1.f / (float)TT);
    float d = __expf(-w);
    float eu = __expf(first[c] * (1.f / (float)TT));
    int cidx = (b * NC2 + j) * TC + c;
    size_t base = ((size_t)(b * TT + j * CL2)) * TC + c;

    float abArr[CL2], bbArr[CL2];
    float ab = CbA[cidx], bb = CbB[cidx];
    #pragma unroll
    for (int i = CL2 - 1; i >= 0; i--) {
        float kk = kp[base + (size_t)i * TC];
        float vv = vp[base + (size_t)i * TC];
        float ek = __expf(kk);
        abArr[i] = ab; bbArr[i] = bb;
        ab = fmaf(d, ab, ek * vv);
        bb = fmaf(d, bb, ek);
    }
    float af = CfA[cidx], bf = CfB[cidx];
    #pragma unroll
    for (int i = 0; i < CL2; i++) {
        size_t idx = base + (size_t)i * TC;
        float kk = kp[idx];
        float vv = vp[idx];
        float srv = srp[idx];
        float ek = __expf(kk);
        float es = ek * eu;
        float num = af + abArr[i] + es * vv;
        float den = bf + bbArr[i] + es;
        float ev = edgep[b * TT + j * CL2 + i];
        float yv = (srv + ev) * (num / den);
        _Float16 yh = (_Float16)yv;
        _Float16 yl = (_Float16)(yv - (float)yh);
        half2v p; p.x = yh; p.y = yl;
        size_t m = (size_t)(b * TT + j * CL2 + i);
        *(half2v*)(Y2 + m * K2 + 2 * c) = p;
        af = fmaf(d, af, ek * vv);
        bf = fmaf(d, bf, ek);
    }
}

// -----------------------------------------------------------------------------
extern "C" void kernel_launch(void* const* d_in, const int* in_sizes, int n_in,
                              void* d_out, int out_size, void* d_ws, size_t ws_size,
                              hipStream_t stream)
{
    const float* x      = (const float*)d_in[0];
    const float* Wk     = (const float*)d_in[1];
    const float* Wv     = (const float*)d_in[2];
    const float* Wr     = (const float*)d_in[3];
    const float* Wo     = (const float*)d_in[4];
    const float* sdecay = (const float*)d_in[5];
    const float* sfirst = (const float*)d_in[6];
    float* out = (float*)d_out;

    char* ws = (char*)d_ws;
    size_t off = 0;
    const size_t MB32 = (size_t)TB * TT * TC * sizeof(float);     // 32 MiB
    const size_t XH   = (size_t)TB * TT * K2 * sizeof(_Float16);  // 32 MiB
    _Float16* X2  = (_Float16*)(ws + off); off += XH;   // reused as Y2
    float* kbuf  = (float*)(ws + off); off += MB32;
    float* vbuf  = (float*)(ws + off); off += MB32;
    float* srbuf = (float*)(ws + off); off += MB32;
    _Float16* W2  = (_Float16*)(ws + off); off += (size_t)3 * TC * K2 * sizeof(_Float16);
    _Float16* Wo2 = (_Float16*)(ws + off); off += (size_t)TC * K2 * sizeof(_Float16);
    float* edge  = (float*)(ws + off); off += (size_t)TB * TT * sizeof(float);
    const size_t CHB = (size_t)TB * NC2 * TC * sizeof(float);     // 1 MiB each
    float* SaF = (float*)(ws + off); off += CHB;
    float* SbF = (float*)(ws + off); off += CHB;
    float* RaB = (float*)(ws + off); off += CHB;
    float* RbB = (float*)(ws + off); off += CHB;
    float* CfA = (float*)(ws + off); off += CHB;
    float* CfB = (float*)(ws + off); off += CHB;
    float* CbA = (float*)(ws + off); off += CHB;
    float* CbB = (float*)(ws + off); off += CHB;

    const int MBLK = (TB * TT) / BM;   // 256
    const int n4 = TB * TT * TC / 4;

    convert_w<<<(4 * TC * TC) / 256, 256, 0, stream>>>(Wk, Wv, Wr, Wo, W2, Wo2);
    convert_x<<<(n4 + 255) / 256, 256, 0, stream>>>(x, X2, n4);
    sobel_edge<<<TB * TT, 256, 0, stream>>>(x, edge);

    // k, v, sr=sigmoid(r)
    gemm_f16<<<dim3(MBLK, 6), 256, 0, stream>>>(
        X2, W2, W2 + (size_t)TC * K2, W2 + (size_t)2 * TC * K2,
        kbuf, vbuf, srbuf, 4);

    wkv_chunk_sums<<<(TB * NC2 * TC) / 256, 256, 0, stream>>>(
        kbuf, vbuf, sdecay, SaF, SbF, RaB, RbB);
    wkv_carries<<<(TB * TC) / 256, 256, 0, stream>>>(
        SaF, SbF, RaB, RbB, sdecay, CfA, CfB, CbA, CbB);
    // combine writes Y2 into X2's buffer (X2 dead after gemm1)
    wkv_combine<<<TB * NC2, 256, 0, stream>>>(
        kbuf, vbuf, srbuf, edge, sdecay, sfirst, CfA, CfB, CbA, CbB, X2);

    // out = y @ Wo^T
    gemm_f16<<<dim3(MBLK, 2), 256, 0, stream>>>(
        X2, Wo2, Wo2, Wo2, out, out, out, 0);
}

// Round 4
// 222.518 us; speedup vs baseline: 1.7700x; 1.1126x over previous
//
#include <hip/hip_runtime.h>
#include <hip/hip_bf16.h>

// Problem constants: B=8, H=W=64, T=4096, C=256
#define TB 8
#define TT 4096
#define TC 256
#define NC2 128   // chunks along T
#define CL2 32    // chunk length

#define K2 512    // f16 split K (2x256)
#define BM 128
#define BN 128
#define BK 64

typedef _Float16 half8 __attribute__((ext_vector_type(8)));
typedef _Float16 half2v __attribute__((ext_vector_type(2)));
typedef float floatx4 __attribute__((ext_vector_type(4)));

#define GLDS16(g, l) __builtin_amdgcn_global_load_lds( \
    (const __attribute__((address_space(1))) void*)(g), \
    (__attribute__((address_space(3))) void*)(l), 16, 0, 0)

// ------- fused Sobel edge gate + x -> f16 hi/lo split (X2, K'=512) ----------
__global__ __launch_bounds__(256) void sobconv(
    const float* __restrict__ x, _Float16* __restrict__ X2,
    float* __restrict__ edge)
{
    int t = blockIdx.x & (TT - 1);
    int b = blockIdx.x >> 12;
    int h = t >> 6, w = t & 63;
    int c = threadIdx.x;

    float n[3][3];
    #pragma unroll
    for (int dh = 0; dh < 3; dh++) {
        int hh = h + dh - 1;
        #pragma unroll
        for (int dw = 0; dw < 3; dw++) {
            int ww = w + dw - 1;
            float val = 0.f;
            if (hh >= 0 && hh < 64 && ww >= 0 && ww < 64)
                val = x[((size_t)(b * TT + (hh << 6) + ww)) * TC + c];
            n[dh][dw] = val;
        }
    }
    // hi/lo split of the center element
    float xc = n[1][1];
    _Float16 hi = (_Float16)xc;
    _Float16 lo = (_Float16)(xc - (float)hi);
    half2v p; p.x = hi; p.y = lo;
    *(half2v*)(X2 + ((size_t)(b * TT + t)) * K2 + 2 * c) = p;

    float gx = (n[0][2] - n[0][0]) + 2.f * (n[1][2] - n[1][0]) + (n[2][2] - n[2][0]);
    float gy = (n[2][0] + 2.f * n[2][1] + n[2][2]) - (n[0][0] + 2.f * n[0][1] + n[0][2]);
    float mag = sqrtf(gx * gx + gy * gy + 1e-8f);

    #pragma unroll
    for (int off = 32; off > 0; off >>= 1) mag += __shfl_down(mag, off, 64);
    __shared__ float part[4];
    if ((threadIdx.x & 63) == 0) part[threadIdx.x >> 6] = mag;
    __syncthreads();
    if (threadIdx.x == 0) {
        float s = part[0] + part[1] + part[2] + part[3];
        edge[blockIdx.x] = 1.f / (1.f + __expf(-s * (1.f / 256.f)));
    }
}

// ------- weight duplicate: W2[n][2k]=W2[n][2k+1]=fp16(W[n][k]) --------------
__global__ __launch_bounds__(256) void convert_w(
    const float* __restrict__ Wk, const float* __restrict__ Wv,
    const float* __restrict__ Wr, const float* __restrict__ Wo,
    _Float16* __restrict__ W2, _Float16* __restrict__ Wo2)
{
    int t = blockIdx.x * 256 + threadIdx.x;     // 4 * 65536
    int wsel = t >> 16;
    int i = t & 65535;
    const float* src = (wsel == 0) ? Wk : (wsel == 1) ? Wv : (wsel == 2) ? Wr : Wo;
    _Float16* dst = (wsel < 3) ? (W2 + (size_t)wsel * TC * K2) : Wo2;
    _Float16 h = (_Float16)src[i];
    half2v p; p.x = h; p.y = h;
    *(half2v*)(dst + 2 * (size_t)i) = p;
}

// ------- MFMA GEMM: C[m,n] = A2[m,:] . W[n,:]  (K'=512, BK=64, swizzled LDS)
// ops: 2 bits per wsel: 0 = fp32 store, 1 = fp32 sigmoid, 2 = f16 exp store
__global__ __launch_bounds__(256) void gemm_f16(
    const _Float16* __restrict__ A2,
    const _Float16* __restrict__ W0, const _Float16* __restrict__ W1,
    const _Float16* __restrict__ W2p,
    void* __restrict__ C0, void* __restrict__ C1, void* __restrict__ C2,
    int ops)
{
    __shared__ __align__(16) char smem[32768];
    _Float16* As = (_Float16*)smem;            // [128][64] 16KB
    _Float16* Bs = (_Float16*)(smem + 16384);  // [128][64] 16KB

    int by = blockIdx.y;
    int wsel = by >> 1;
    const _Float16* W = (wsel == 0) ? W0 : (wsel == 1) ? W1 : W2p;
    void* Cc          = (wsel == 0) ? C0 : (wsel == 1) ? C1 : C2;
    int col0 = (by & 1) * BN;
    int row0 = blockIdx.x * BM;
    int op = (ops >> (2 * wsel)) & 3;

    int tid = threadIdx.x;
    int lane = tid & 63;
    int wv = tid >> 6;
    int qm = (wv >> 1) * 64;
    int qn = (wv & 1) * 64;

    const _Float16* Ag = A2 + (size_t)row0 * K2;
    const _Float16* Bg = W + (size_t)col0 * K2;

    floatx4 acc[4][4];
    #pragma unroll
    for (int i = 0; i < 4; i++)
        #pragma unroll
        for (int j = 0; j < 4; j++)
            acc[i][j] = (floatx4){0.f, 0.f, 0.f, 0.f};

    for (int kb = 0; kb < K2; kb += BK) {
        __syncthreads();
        #pragma unroll
        for (int i = 0; i < 4; i++) {
            int seg = i * 256 + tid;          // 1024 segs of 16B per matrix
            int row = seg >> 3;
            int s = seg & 7;
            int sg = s ^ (row & 7);           // swizzled global k-seg
            GLDS16(Ag + (size_t)row * K2 + kb + sg * 8, &As[seg * 8]);
            GLDS16(Bg + (size_t)row * K2 + kb + sg * 8, &Bs[seg * 8]);
        }
        __syncthreads();
        #pragma unroll
        for (int kk = 0; kk < 2; kk++) {
            int sl = kk * 4 + (lane >> 4);
            half8 a[4], b[4];
            #pragma unroll
            for (int i = 0; i < 4; i++) {
                int ra = qm + i * 16 + (lane & 15);
                a[i] = *(const half8*)&As[ra * BK + ((sl ^ (ra & 7)) * 8)];
                int rb = qn + i * 16 + (lane & 15);
                b[i] = *(const half8*)&Bs[rb * BK + ((sl ^ (rb & 7)) * 8)];
            }
            #pragma unroll
            for (int i = 0; i < 4; i++)
                #pragma unroll
                for (int j = 0; j < 4; j++)
                    acc[i][j] = __builtin_amdgcn_mfma_f32_16x16x32_f16(
                        a[i], b[j], acc[i][j], 0, 0, 0);
        }
    }

    // D mapping (16x16): row m = (lane>>4)*4 + reg, col n = lane&15
    int mr0 = (lane >> 4) * 4;
    int nc = lane & 15;
    if (op == 2) {
        // f16 exp output via swizzled LDS tile + coalesced dwordx4 stores
        __syncthreads();
        ushort* tile = (ushort*)smem;          // [128][128] ushort = 32KB
        #pragma unroll
        for (int i = 0; i < 4; i++)
            #pragma unroll
            for (int r = 0; r < 4; r++) {
                int ml = qm + i * 16 + mr0 + r;
                #pragma unroll
                for (int j = 0; j < 4; j++) {
                    int nl = qn + j * 16 + nc;
                    float vv = __expf(acc[i][j][r]);
                    _Float16 hh = (_Float16)vv;
                    tile[ml * 128 + (nl ^ (((ml >> 2) & 3) << 4))] = *(ushort*)&hh;
                }
            }
        __syncthreads();
        _Float16* Ch = (_Float16*)Cc;
        #pragma unroll
        for (int k = 0; k < 8; k++) {
            int seg = k * 256 + tid;           // 2048 segs of 16B
            int tr = seg >> 4;
            int ts = seg & 15;
            int ts2 = ts ^ (((tr >> 2) & 3) << 1);
            float4 val = *(const float4*)&tile[tr * 128 + ts2 * 8];
            ((float4*)(Ch + (size_t)(row0 + tr) * TC + col0))[ts] = val;
        }
    } else {
        float* Cf = (float*)Cc;
        #pragma unroll
        for (int i = 0; i < 4; i++) {
            #pragma unroll
            for (int r = 0; r < 4; r++) {
                int m = row0 + qm + i * 16 + mr0 + r;
                float* crow = Cf + (size_t)m * TC + col0 + qn;
                #pragma unroll
                for (int j = 0; j < 4; j++) {
                    float vvv = acc[i][j][r];
                    if (op == 1) vvv = 1.f / (1.f + __expf(-vvv));
                    crow[j * 16 + nc] = vvv;
                }
            }
        }
    }
}

// ------- WKV phase A: per-chunk local sums (ek f16 input) --------------------
__global__ __launch_bounds__(256) void wkv_chunk_sums(
    const _Float16* __restrict__ ekp, const float* __restrict__ vp,
    const float* __restrict__ decay,
    float* __restrict__ SaF, float* __restrict__ SbF,
    float* __restrict__ RaB, float* __restrict__ RbB)
{
    int tid = blockIdx.x * 256 + threadIdx.x;   // B*NC2*C
    int c = tid & 255;
    int j = (tid >> 8) & (NC2 - 1);
    int b = tid >> 15;
    float w = decay[c] * (1.f / (float)TT);
    float d = __expf(-w);
    size_t base = ((size_t)(b * TT + j * CL2)) * TC + c;
    float Sa = 0.f, Sb = 0.f, Ra = 0.f, Rb = 0.f, pw = 1.f;
    #pragma unroll
    for (int i = 0; i < CL2; i++) {
        float ek = (float)ekp[base + (size_t)i * TC];
        float vv = vp[base + (size_t)i * TC];
        float ekv = ek * vv;
        Sa = fmaf(d, Sa, ekv);
        Sb = fmaf(d, Sb, ek);
        Ra = fmaf(pw, ekv, Ra);
        Rb = fmaf(pw, ek, Rb);
        pw *= d;
    }
    int idx = (b * NC2 + j) * TC + c;
    SaF[idx] = Sa; SbF[idx] = Sb; RaB[idx] = Ra; RbB[idx] = Rb;
}

// ------- WKV phase B: Kogge-Stone wave scan over 128 chunks ------------------
// ONE WAVE per (b,c) column: 2048 waves total -> 512 blocks of 256 threads.
// lane holds chunks 2l,2l+1 (fwd) and the mirrored pair (bwd).
__global__ __launch_bounds__(256) void wkv_carries(
    const float* __restrict__ SaF, const float* __restrict__ SbF,
    const float* __restrict__ RaB, const float* __restrict__ RbB,
    const float* __restrict__ decay,
    float* __restrict__ CfA, float* __restrict__ CfB,
    float* __restrict__ CbA, float* __restrict__ CbB)
{
    int gw = (blockIdx.x * 256 + threadIdx.x) >> 6;   // 0..2047
    int lane = threadIdx.x & 63;
    int c = gw & 255, b = gw >> 8;
    float w = decay[c] * (1.f / (float)TT);
    float D = __expf(-(float)CL2 * w);
    int base = b * NC2 * TC + c;
    int j0 = 2 * lane, j1 = 2 * lane + 1;
    int r0 = NC2 - 1 - j0, r1 = NC2 - 2 - j0;

    float sa0 = SaF[base + j0 * TC], sa1 = SaF[base + j1 * TC];
    float sb0 = SbF[base + j0 * TC], sb1 = SbF[base + j1 * TC];
    float qa0 = RaB[base + r0 * TC], qa1 = RaB[base + r1 * TC];
    float qb0 = RbB[base + r0 * TC], qb1 = RbB[base + r1 * TC];

    float pa = fmaf(D, sa0, sa1), pb = fmaf(D, sb0, sb1);
    float ra = fmaf(D, qa0, qa1), rb = fmaf(D, qb0, qb1);

    float dp = D * D;   // decay of a 2-chunk segment
    #pragma unroll
    for (int off = 1; off < 64; off <<= 1) {
        float ta = __shfl_up(pa, off, 64);
        float tb = __shfl_up(pb, off, 64);
        float ua = __shfl_up(ra, off, 64);
        float ub = __shfl_up(rb, off, 64);
        if (lane >= off) {
            pa = fmaf(dp, ta, pa); pb = fmaf(dp, tb, pb);
            ra = fmaf(dp, ua, ra); rb = fmaf(dp, ub, rb);
        }
        dp = dp * dp;
    }
    float ppa = __shfl_up(pa, 1, 64);
    float ppb = __shfl_up(pb, 1, 64);
    float pra = __shfl_up(ra, 1, 64);
    float prb = __shfl_up(rb, 1, 64);
    if (lane == 0) { ppa = 0.f; ppb = 0.f; pra = 0.f; prb = 0.f; }

    CfA[base + j0 * TC] = ppa;
    CfA[base + j1 * TC] = fmaf(D, ppa, sa0);
    CfB[base + j0 * TC] = ppb;
    CfB[base + j1 * TC] = fmaf(D, ppb, sb0);
    CbA[base + r0 * TC] = pra;
    CbA[base + r1 * TC] = fmaf(D, pra, qa0);
    CbB[base + r0 * TC] = prb;
    CbB[base + r1 * TC] = fmaf(D, prb, qb0);
}

// ------- WKV phase C: combine + gate -> Y2 (f16 hi/lo pairs) -----------------
__global__ __launch_bounds__(256) void wkv_combine(
    const _Float16* __restrict__ ekp, const float* __restrict__ vp,
    const float* __restrict__ srp, const float* __restrict__ edgep,
    const float* __restrict__ decay, const float* __restrict__ first,
    const float* __restrict__ CfA, const float* __restrict__ CfB,
    const float* __restrict__ CbA, const float* __restrict__ CbB,
    _Float16* __restrict__ Y2)
{
    int bid = blockIdx.x;            // B*NC2 = 1024
    int j = bid & (NC2 - 1);
    int b = bid >> 7;
    int c = threadIdx.x;

    float w = decay[c] * (1.f / (float)TT);
    float d = __expf(-w);
    float eu = __expf(first[c] * (1.f / (float)TT));
    int cidx = (b * NC2 + j) * TC + c;
    size_t base = ((size_t)(b * TT + j * CL2)) * TC + c;

    float abArr[CL2], bbArr[CL2];
    float ab = CbA[cidx], bb = CbB[cidx];
    #pragma unroll
    for (int i = CL2 - 1; i >= 0; i--) {
        float ek = (float)ekp[base + (size_t)i * TC];
        float vv = vp[base + (size_t)i * TC];
        abArr[i] = ab; bbArr[i] = bb;
        ab = fmaf(d, ab, ek * vv);
        bb = fmaf(d, bb, ek);
    }
    float af = CfA[cidx], bf = CfB[cidx];
    #pragma unroll
    for (int i = 0; i < CL2; i++) {
        size_t idx = base + (size_t)i * TC;
        float ek = (float)ekp[idx];
        float vv = vp[idx];
        float srv = srp[idx];
        float es = ek * eu;
        float num = af + abArr[i] + es * vv;
        float den = bf + bbArr[i] + es;
        float ev = edgep[b * TT + j * CL2 + i];
        float yv = (srv + ev) * (num / den);
        _Float16 yh = (_Float16)yv;
        _Float16 yl = (_Float16)(yv - (float)yh);
        half2v p; p.x = yh; p.y = yl;
        size_t m = (size_t)(b * TT + j * CL2 + i);
        *(half2v*)(Y2 + m * K2 + 2 * c) = p;
        af = fmaf(d, af, ek * vv);
        bf = fmaf(d, bf, ek);
    }
}

// -----------------------------------------------------------------------------
extern "C" void kernel_launch(void* const* d_in, const int* in_sizes, int n_in,
                              void* d_out, int out_size, void* d_ws, size_t ws_size,
                              hipStream_t stream)
{
    const float* x      = (const float*)d_in[0];
    const float* Wk     = (const float*)d_in[1];
    const float* Wv     = (const float*)d_in[2];
    const float* Wr     = (const float*)d_in[3];
    const float* Wo     = (const float*)d_in[4];
    const float* sdecay = (const float*)d_in[5];
    const float* sfirst = (const float*)d_in[6];
    float* out = (float*)d_out;

    char* ws = (char*)d_ws;
    size_t off = 0;
    const size_t MB32 = (size_t)TB * TT * TC * sizeof(float);     // 32 MiB
    const size_t XH   = (size_t)TB * TT * K2 * sizeof(_Float16);  // 32 MiB
    _Float16* X2   = (_Float16*)(ws + off); off += XH;   // reused as Y2
    _Float16* ekh  = (_Float16*)(ws + off); off += MB32 / 2;
    float* vbuf  = (float*)(ws + off); off += MB32;
    float* srbuf = (float*)(ws + off); off += MB32;
    _Float16* W2  = (_Float16*)(ws + off); off += (size_t)3 * TC * K2 * sizeof(_Float16);
    _Float16* Wo2 = (_Float16*)(ws + off); off += (size_t)TC * K2 * sizeof(_Float16);
    float* edge  = (float*)(ws + off); off += (size_t)TB * TT * sizeof(float);
    const size_t CHB = (size_t)TB * NC2 * TC * sizeof(float);     // 1 MiB each
    float* SaF = (float*)(ws + off); off += CHB;
    float* SbF = (float*)(ws + off); off += CHB;
    float* RaB = (float*)(ws + off); off += CHB;
    float* RbB = (float*)(ws + off); off += CHB;
    float* CfA = (float*)(ws + off); off += CHB;
    float* CfB = (float*)(ws + off); off += CHB;
    float* CbA = (float*)(ws + off); off += CHB;
    float* CbB = (float*)(ws + off); off += CHB;

    const int MBLK = (TB * TT) / BM;   // 256

    convert_w<<<(4 * TC * TC) / 256, 256, 0, stream>>>(Wk, Wv, Wr, Wo, W2, Wo2);
    sobconv<<<TB * TT, 256, 0, stream>>>(x, X2, edge);

    // ek = exp(x@Wk^T) (f16), v (fp32), sr = sigmoid(x@Wr^T) (fp32)
    int ops1 = (2 << 0) | (0 << 2) | (1 << 4);
    gemm_f16<<<dim3(MBLK, 6), 256, 0, stream>>>(
        X2, W2, W2 + (size_t)TC * K2, W2 + (size_t)2 * TC * K2,
        ekh, vbuf, srbuf, ops1);

    wkv_chunk_sums<<<(TB * NC2 * TC) / 256, 256, 0, stream>>>(
        ekh, vbuf, sdecay, SaF, SbF, RaB, RbB);
    // one wave per (b,c): 2048 waves -> 512 blocks (r3 bug: was 8 blocks)
    wkv_carries<<<(TB * TC * 64) / 256, 256, 0, stream>>>(
        SaF, SbF, RaB, RbB, sdecay, CfA, CfB, CbA, CbB);
    wkv_combine<<<TB * NC2, 256, 0, stream>>>(
        ekh, vbuf, srbuf, edge, sdecay, sfirst, CfA, CfB, CbA, CbB, X2);

    // out = y @ Wo^T
    gemm_f16<<<dim3(MBLK, 2), 256, 0, stream>>>(
        X2, Wo2, Wo2, Wo2, out, out, out, 0);
}

// Round 5
// 219.284 us; speedup vs baseline: 1.7961x; 1.0147x over previous
//
#include <hip/hip_runtime.h>
#include <hip/hip_bf16.h>

// Problem constants: B=8, H=W=64, T=4096, C=256
#define TB 8
#define TT 4096
#define TC 256
#define NC2 128   // chunks along T
#define CL2 32    // chunk length

typedef _Float16 half8 __attribute__((ext_vector_type(8)));
typedef _Float16 half4v __attribute__((ext_vector_type(4)));
typedef float floatx4 __attribute__((ext_vector_type(4)));

#define GLDS16(g, l) __builtin_amdgcn_global_load_lds( \
    (const __attribute__((address_space(1))) void*)(g), \
    (__attribute__((address_space(3))) void*)(l), 16, 0, 0)

// ------- prep: sobel edge gate + x hi/lo split planes + W -> f16 -------------
__global__ __launch_bounds__(256) void prep(
    const float* __restrict__ x,
    const float* __restrict__ Wk, const float* __restrict__ Wv,
    const float* __restrict__ Wr, const float* __restrict__ Wo,
    _Float16* __restrict__ Xh, _Float16* __restrict__ Xl,
    _Float16* __restrict__ Wf, float* __restrict__ edge)
{
    if (blockIdx.x >= TB * TT) {
        // weight convert: 4 * 65536 floats, 4 per thread
        int t4 = (blockIdx.x - TB * TT) * 256 + threadIdx.x;
        int f = t4 * 4;
        int wsel = f >> 16;
        int i = f & 65535;
        const float* src = (wsel == 0) ? Wk : (wsel == 1) ? Wv :
                           (wsel == 2) ? Wr : Wo;
        float4 v = *(const float4*)(src + i);
        half4v h;
        h.x = (_Float16)v.x; h.y = (_Float16)v.y;
        h.z = (_Float16)v.z; h.w = (_Float16)v.w;
        *(half4v*)(Wf + (size_t)wsel * 65536 + i) = h;
        return;
    }
    int t = blockIdx.x & (TT - 1);
    int b = blockIdx.x >> 12;
    int h = t >> 6, w = t & 63;
    int c = threadIdx.x;

    float n[3][3];
    #pragma unroll
    for (int dh = 0; dh < 3; dh++) {
        int hh = h + dh - 1;
        #pragma unroll
        for (int dw = 0; dw < 3; dw++) {
            int ww = w + dw - 1;
            float val = 0.f;
            if (hh >= 0 && hh < 64 && ww >= 0 && ww < 64)
                val = x[((size_t)(b * TT + (hh << 6) + ww)) * TC + c];
            n[dh][dw] = val;
        }
    }
    float xc = n[1][1];
    _Float16 hi = (_Float16)xc;
    _Float16 lo = (_Float16)(xc - (float)hi);
    size_t mi = (size_t)(b * TT + t) * TC + c;
    Xh[mi] = hi;
    Xl[mi] = lo;

    float gx = (n[0][2] - n[0][0]) + 2.f * (n[1][2] - n[1][0]) + (n[2][2] - n[2][0]);
    float gy = (n[2][0] + 2.f * n[2][1] + n[2][2]) - (n[0][0] + 2.f * n[0][1] + n[0][2]);
    float mag = sqrtf(gx * gx + gy * gy + 1e-8f);

    #pragma unroll
    for (int off = 32; off > 0; off >>= 1) mag += __shfl_down(mag, off, 64);
    __shared__ float part[4];
    if ((threadIdx.x & 63) == 0) part[threadIdx.x >> 6] = mag;
    __syncthreads();
    if (threadIdx.x == 0) {
        float s = part[0] + part[1] + part[2] + part[3];
        edge[blockIdx.x] = 1.f / (1.f + __expf(-s * (1.f / 256.f)));
    }
}

// ------- MFMA GEMM: C[m,n] = (Xh[m,:]+Xl[m,:]) . W[n,:], K=256, BN=256 ------
// 128x256 tile, 4 waves of 64x128; two MFMAs (hi,lo) share each b-frag.
// op: 0 = fp32 store, 1 = fp32 sigmoid, 2 = f16 exp store
__global__ __launch_bounds__(256, 2) void gemm_split(
    const _Float16* __restrict__ Ah_g, const _Float16* __restrict__ Al_g,
    const _Float16* __restrict__ W0, const _Float16* __restrict__ W1,
    const _Float16* __restrict__ W2p,
    void* __restrict__ C0, void* __restrict__ C1, void* __restrict__ C2,
    int ops)
{
    __shared__ __align__(16) _Float16 smem[16384];   // 32 KB
    _Float16* Ah = smem;            // [128][32]
    _Float16* Al = smem + 4096;     // [128][32]
    _Float16* Bs = smem + 8192;     // [256][32]

    int wsel = blockIdx.y;
    const _Float16* W = (wsel == 0) ? W0 : (wsel == 1) ? W1 : W2p;
    void* Cc          = (wsel == 0) ? C0 : (wsel == 1) ? C1 : C2;
    int op = (ops >> (2 * wsel)) & 3;
    int row0 = blockIdx.x * 128;

    int tid = threadIdx.x;
    int lane = tid & 63;
    int wv = tid >> 6;
    int qm = (wv >> 1) * 64;
    int qn = (wv & 1) * 128;

    floatx4 acc[4][8];
    #pragma unroll
    for (int i = 0; i < 4; i++)
        #pragma unroll
        for (int j = 0; j < 8; j++)
            acc[i][j] = (floatx4){0.f, 0.f, 0.f, 0.f};

    for (int kb = 0; kb < 256; kb += 32) {
        __syncthreads();
        #pragma unroll
        for (int r = 0; r < 2; r++) {
            int q = r * 256 + tid;           // A segs: 512 of 16B per plane
            int row = q >> 2;
            int s = q & 3;
            int g = (s - row - (row >> 2)) & 3;   // bank-rotation inverse
            size_t goff = (size_t)(row0 + row) * TC + kb + g * 8;
            GLDS16(Ah_g + goff, &Ah[q * 8]);
            GLDS16(Al_g + goff, &Al[q * 8]);
        }
        #pragma unroll
        for (int r = 0; r < 4; r++) {
            int q = r * 256 + tid;           // B segs: 1024 of 16B
            int row = q >> 2;
            int s = q & 3;
            int g = (s - row - (row >> 2)) & 3;
            GLDS16(W + (size_t)row * TC + kb + g * 8, &Bs[q * 8]);
        }
        __syncthreads();
        int sl = lane >> 4;
        half8 ah[4], al[4], b[8];
        #pragma unroll
        for (int i = 0; i < 4; i++) {
            int ra = qm + i * 16 + (lane & 15);
            int sa = (sl + ra + (ra >> 2)) & 3;
            ah[i] = *(const half8*)&Ah[ra * 32 + sa * 8];
            al[i] = *(const half8*)&Al[ra * 32 + sa * 8];
        }
        #pragma unroll
        for (int j = 0; j < 8; j++) {
            int rb = qn + j * 16 + (lane & 15);
            int sb = (sl + rb + (rb >> 2)) & 3;
            b[j] = *(const half8*)&Bs[rb * 32 + sb * 8];
        }
        #pragma unroll
        for (int i = 0; i < 4; i++)
            #pragma unroll
            for (int j = 0; j < 8; j++) {
                acc[i][j] = __builtin_amdgcn_mfma_f32_16x16x32_f16(
                    ah[i], b[j], acc[i][j], 0, 0, 0);
                acc[i][j] = __builtin_amdgcn_mfma_f32_16x16x32_f16(
                    al[i], b[j], acc[i][j], 0, 0, 0);
            }
    }

    // D mapping (16x16): row m = (lane>>4)*4 + reg, col n = lane&15
    int mr0 = (lane >> 4) * 4;
    int nc = lane & 15;
    #pragma unroll
    for (int i = 0; i < 4; i++) {
        #pragma unroll
        for (int r = 0; r < 4; r++) {
            int m = row0 + qm + i * 16 + mr0 + r;
            if (op == 2) {
                _Float16* crow = (_Float16*)Cc + (size_t)m * TC + qn + nc;
                #pragma unroll
                for (int j = 0; j < 8; j++)
                    crow[j * 16] = (_Float16)__expf(acc[i][j][r]);
            } else if (op == 1) {
                float* crow = (float*)Cc + (size_t)m * TC + qn + nc;
                #pragma unroll
                for (int j = 0; j < 8; j++)
                    crow[j * 16] = 1.f / (1.f + __expf(-acc[i][j][r]));
            } else {
                float* crow = (float*)Cc + (size_t)m * TC + qn + nc;
                #pragma unroll
                for (int j = 0; j < 8; j++)
                    crow[j * 16] = acc[i][j][r];
            }
        }
    }
}

// ------- WKV phase A: per-chunk local sums (ek f16 input) --------------------
__global__ __launch_bounds__(256) void wkv_chunk_sums(
    const _Float16* __restrict__ ekp, const float* __restrict__ vp,
    const float* __restrict__ decay,
    float* __restrict__ SaF, float* __restrict__ SbF,
    float* __restrict__ RaB, float* __restrict__ RbB)
{
    int tid = blockIdx.x * 256 + threadIdx.x;   // B*NC2*C
    int c = tid & 255;
    int j = (tid >> 8) & (NC2 - 1);
    int b = tid >> 15;
    float w = decay[c] * (1.f / (float)TT);
    float d = __expf(-w);
    size_t base = ((size_t)(b * TT + j * CL2)) * TC + c;
    float Sa = 0.f, Sb = 0.f, Ra = 0.f, Rb = 0.f, pw = 1.f;
    #pragma unroll
    for (int i = 0; i < CL2; i++) {
        float ek = (float)ekp[base + (size_t)i * TC];
        float vv = vp[base + (size_t)i * TC];
        float ekv = ek * vv;
        Sa = fmaf(d, Sa, ekv);
        Sb = fmaf(d, Sb, ek);
        Ra = fmaf(pw, ekv, Ra);
        Rb = fmaf(pw, ek, Rb);
        pw *= d;
    }
    int idx = (b * NC2 + j) * TC + c;
    SaF[idx] = Sa; SbF[idx] = Sb; RaB[idx] = Ra; RbB[idx] = Rb;
}

// ------- WKV phase B: Kogge-Stone wave scan over 128 chunks ------------------
// ONE WAVE per (b,c): 2048 waves -> 512 blocks of 256 threads.
__global__ __launch_bounds__(256) void wkv_carries(
    const float* __restrict__ SaF, const float* __restrict__ SbF,
    const float* __restrict__ RaB, const float* __restrict__ RbB,
    const float* __restrict__ decay,
    float* __restrict__ CfA, float* __restrict__ CfB,
    float* __restrict__ CbA, float* __restrict__ CbB)
{
    int gw = (blockIdx.x * 256 + threadIdx.x) >> 6;   // 0..2047
    int lane = threadIdx.x & 63;
    int c = gw & 255, b = gw >> 8;
    float w = decay[c] * (1.f / (float)TT);
    float D = __expf(-(float)CL2 * w);
    int base = b * NC2 * TC + c;
    int j0 = 2 * lane, j1 = 2 * lane + 1;
    int r0 = NC2 - 1 - j0, r1 = NC2 - 2 - j0;

    float sa0 = SaF[base + j0 * TC], sa1 = SaF[base + j1 * TC];
    float sb0 = SbF[base + j0 * TC], sb1 = SbF[base + j1 * TC];
    float qa0 = RaB[base + r0 * TC], qa1 = RaB[base + r1 * TC];
    float qb0 = RbB[base + r0 * TC], qb1 = RbB[base + r1 * TC];

    float pa = fmaf(D, sa0, sa1), pb = fmaf(D, sb0, sb1);
    float ra = fmaf(D, qa0, qa1), rb = fmaf(D, qb0, qb1);

    float dp = D * D;
    #pragma unroll
    for (int off = 1; off < 64; off <<= 1) {
        float ta = __shfl_up(pa, off, 64);
        float tb = __shfl_up(pb, off, 64);
        float ua = __shfl_up(ra, off, 64);
        float ub = __shfl_up(rb, off, 64);
        if (lane >= off) {
            pa = fmaf(dp, ta, pa); pb = fmaf(dp, tb, pb);
            ra = fmaf(dp, ua, ra); rb = fmaf(dp, ub, rb);
        }
        dp = dp * dp;
    }
    float ppa = __shfl_up(pa, 1, 64);
    float ppb = __shfl_up(pb, 1, 64);
    float pra = __shfl_up(ra, 1, 64);
    float prb = __shfl_up(rb, 1, 64);
    if (lane == 0) { ppa = 0.f; ppb = 0.f; pra = 0.f; prb = 0.f; }

    CfA[base + j0 * TC] = ppa;
    CfA[base + j1 * TC] = fmaf(D, ppa, sa0);
    CfB[base + j0 * TC] = ppb;
    CfB[base + j1 * TC] = fmaf(D, ppb, sb0);
    CbA[base + r0 * TC] = pra;
    CbA[base + r1 * TC] = fmaf(D, pra, qa0);
    CbB[base + r0 * TC] = prb;
    CbB[base + r1 * TC] = fmaf(D, prb, qb0);
}

// ------- WKV phase C: combine + gate -> Yh/Yl planes -------------------------
__global__ __launch_bounds__(256) void wkv_combine(
    const _Float16* __restrict__ ekp, const float* __restrict__ vp,
    const float* __restrict__ srp, const float* __restrict__ edgep,
    const float* __restrict__ decay, const float* __restrict__ first,
    const float* __restrict__ CfA, const float* __restrict__ CfB,
    const float* __restrict__ CbA, const float* __restrict__ CbB,
    _Float16* __restrict__ Yh, _Float16* __restrict__ Yl)
{
    int bid = blockIdx.x;            // B*NC2 = 1024
    int j = bid & (NC2 - 1);
    int b = bid >> 7;
    int c = threadIdx.x;

    float w = decay[c] * (1.f / (float)TT);
    float d = __expf(-w);
    float eu = __expf(first[c] * (1.f / (float)TT));
    int cidx = (b * NC2 + j) * TC + c;
    size_t base = ((size_t)(b * TT + j * CL2)) * TC + c;

    float abArr[CL2], bbArr[CL2];
    float ab = CbA[cidx], bb = CbB[cidx];
    #pragma unroll
    for (int i = CL2 - 1; i >= 0; i--) {
        float ek = (float)ekp[base + (size_t)i * TC];
        float vv = vp[base + (size_t)i * TC];
        abArr[i] = ab; bbArr[i] = bb;
        ab = fmaf(d, ab, ek * vv);
        bb = fmaf(d, bb, ek);
    }
    float af = CfA[cidx], bf = CfB[cidx];
    #pragma unroll
    for (int i = 0; i < CL2; i++) {
        size_t idx = base + (size_t)i * TC;
        float ek = (float)ekp[idx];
        float vv = vp[idx];
        float srv = srp[idx];
        float es = ek * eu;
        float num = af + abArr[i] + es * vv;
        float den = bf + bbArr[i] + es;
        float ev = edgep[b * TT + j * CL2 + i];
        float yv = (srv + ev) * (num / den);
        _Float16 yh = (_Float16)yv;
        _Float16 yl = (_Float16)(yv - (float)yh);
        Yh[idx] = yh;
        Yl[idx] = yl;
        af = fmaf(d, af, ek * vv);
        bf = fmaf(d, bf, ek);
    }
}

// -----------------------------------------------------------------------------
extern "C" void kernel_launch(void* const* d_in, const int* in_sizes, int n_in,
                              void* d_out, int out_size, void* d_ws, size_t ws_size,
                              hipStream_t stream)
{
    const float* x      = (const float*)d_in[0];
    const float* Wk     = (const float*)d_in[1];
    const float* Wv     = (const float*)d_in[2];
    const float* Wr     = (const float*)d_in[3];
    const float* Wo     = (const float*)d_in[4];
    const float* sdecay = (const float*)d_in[5];
    const float* sfirst = (const float*)d_in[6];
    float* out = (float*)d_out;

    char* ws = (char*)d_ws;
    size_t off = 0;
    const size_t PH = (size_t)TB * TT * TC * sizeof(_Float16);   // 16 MiB plane
    _Float16* Xh  = (_Float16*)(ws + off); off += PH;   // reused as Yh
    _Float16* Xl  = (_Float16*)(ws + off); off += PH;   // reused as Yl
    _Float16* ekh = (_Float16*)(ws + off); off += PH;
    float* vbuf  = (float*)(ws + off); off += 2 * PH;
    float* srbuf = (float*)(ws + off); off += 2 * PH;
    _Float16* Wf = (_Float16*)(ws + off); off += (size_t)4 * TC * TC * sizeof(_Float16);
    float* edge  = (float*)(ws + off); off += (size_t)TB * TT * sizeof(float);
    const size_t CHB = (size_t)TB * NC2 * TC * sizeof(float);    // 1 MiB each
    float* SaF = (float*)(ws + off); off += CHB;
    float* SbF = (float*)(ws + off); off += CHB;
    float* RaB = (float*)(ws + off); off += CHB;
    float* RbB = (float*)(ws + off); off += CHB;
    float* CfA = (float*)(ws + off); off += CHB;
    float* CfB = (float*)(ws + off); off += CHB;
    float* CbA = (float*)(ws + off); off += CHB;
    float* CbB = (float*)(ws + off); off += CHB;

    _Float16* WfK = Wf;
    _Float16* WfV = Wf + (size_t)TC * TC;
    _Float16* WfR = Wf + (size_t)2 * TC * TC;
    _Float16* WfO = Wf + (size_t)3 * TC * TC;

    // 1) sobel + x split + W convert (one launch)
    prep<<<TB * TT + 256, 256, 0, stream>>>(x, Wk, Wv, Wr, Wo, Xh, Xl, Wf, edge);

    // 2) ek = exp(x@Wk^T) f16, v fp32, sr = sigmoid(x@Wr^T) fp32
    int ops1 = 2 | (0 << 2) | (1 << 4);
    gemm_split<<<dim3((TB * TT) / 128, 3), 256, 0, stream>>>(
        Xh, Xl, WfK, WfV, WfR, ekh, vbuf, srbuf, ops1);

    // 3) chunk-local sums
    wkv_chunk_sums<<<(TB * NC2 * TC) / 256, 256, 0, stream>>>(
        ekh, vbuf, sdecay, SaF, SbF, RaB, RbB);
    // 4) carries: one wave per (b,c) -> 512 blocks
    wkv_carries<<<(TB * TC * 64) / 256, 256, 0, stream>>>(
        SaF, SbF, RaB, RbB, sdecay, CfA, CfB, CbA, CbB);
    // 5) combine -> Yh/Yl (reuse Xh/Xl)
    wkv_combine<<<TB * NC2, 256, 0, stream>>>(
        ekh, vbuf, srbuf, edge, sdecay, sfirst, CfA, CfB, CbA, CbB, Xh, Xl);

    // 6) out = y @ Wo^T
    gemm_split<<<dim3((TB * TT) / 128, 1), 256, 0, stream>>>(
        Xh, Xl, WfO, WfO, WfO, out, out, out, 0);
}

// Round 7
// 215.084 us; speedup vs baseline: 1.8312x; 1.0195x over previous
//
#include <hip/hip_runtime.h>
#include <hip/hip_bf16.h>

// Problem constants: B=8, H=W=64, T=4096, C=256
#define TB 8
#define TT 4096
#define TC 256
#define NC2 128   // chunks along T
#define CL2 32    // chunk length

typedef _Float16 half8 __attribute__((ext_vector_type(8)));
typedef _Float16 half4v __attribute__((ext_vector_type(4)));
typedef float floatx4 __attribute__((ext_vector_type(4)));

#define GLDS16(g, l) __builtin_amdgcn_global_load_lds( \
    (const __attribute__((address_space(1))) void*)(g), \
    (__attribute__((address_space(3))) void*)(l), 16, 0, 0)

// ------- prep: sobel edge gate + x hi/lo split planes + W -> f16 -------------
__global__ __launch_bounds__(256) void prep(
    const float* __restrict__ x,
    const float* __restrict__ Wk, const float* __restrict__ Wv,
    const float* __restrict__ Wr, const float* __restrict__ Wo,
    _Float16* __restrict__ Xh, _Float16* __restrict__ Xl,
    _Float16* __restrict__ Wf, float* __restrict__ edge)
{
    if (blockIdx.x >= TB * TT) {
        int t4 = (blockIdx.x - TB * TT) * 256 + threadIdx.x;
        int f = t4 * 4;
        int wsel = f >> 16;
        int i = f & 65535;
        const float* src = (wsel == 0) ? Wk : (wsel == 1) ? Wv :
                           (wsel == 2) ? Wr : Wo;
        float4 v = *(const float4*)(src + i);
        half4v h;
        h.x = (_Float16)v.x; h.y = (_Float16)v.y;
        h.z = (_Float16)v.z; h.w = (_Float16)v.w;
        *(half4v*)(Wf + (size_t)wsel * 65536 + i) = h;
        return;
    }
    int t = blockIdx.x & (TT - 1);
    int b = blockIdx.x >> 12;
    int h = t >> 6, w = t & 63;
    int c = threadIdx.x;

    float n[3][3];
    #pragma unroll
    for (int dh = 0; dh < 3; dh++) {
        int hh = h + dh - 1;
        #pragma unroll
        for (int dw = 0; dw < 3; dw++) {
            int ww = w + dw - 1;
            float val = 0.f;
            if (hh >= 0 && hh < 64 && ww >= 0 && ww < 64)
                val = x[((size_t)(b * TT + (hh << 6) + ww)) * TC + c];
            n[dh][dw] = val;
        }
    }
    float xc = n[1][1];
    _Float16 hi = (_Float16)xc;
    _Float16 lo = (_Float16)(xc - (float)hi);
    size_t mi = (size_t)(b * TT + t) * TC + c;
    Xh[mi] = hi;
    Xl[mi] = lo;

    float gx = (n[0][2] - n[0][0]) + 2.f * (n[1][2] - n[1][0]) + (n[2][2] - n[2][0]);
    float gy = (n[2][0] + 2.f * n[2][1] + n[2][2]) - (n[0][0] + 2.f * n[0][1] + n[0][2]);
    float mag = sqrtf(gx * gx + gy * gy + 1e-8f);

    #pragma unroll
    for (int off = 32; off > 0; off >>= 1) mag += __shfl_down(mag, off, 64);
    __shared__ float part[4];
    if ((threadIdx.x & 63) == 0) part[threadIdx.x >> 6] = mag;
    __syncthreads();
    if (threadIdx.x == 0) {
        float s = part[0] + part[1] + part[2] + part[3];
        edge[blockIdx.x] = 1.f / (1.f + __expf(-s * (1.f / 256.f)));
    }
}

// ------- MFMA GEMM: C[m,n] = (Xh+Xl)[m,:] . W[n,:], tile 128x256, K=256 -----
// r5-proven geometry: 4 waves of 64x128, (256,2), 32 KB LDS.
// op: 0=fp32 store, 1=f16 sigmoid, 2=f16 exp, 3=f16 plain
__global__ __launch_bounds__(256, 2) void gemm_split(
    const _Float16* __restrict__ Ah_g, const _Float16* __restrict__ Al_g,
    const _Float16* __restrict__ W0, const _Float16* __restrict__ W1,
    const _Float16* __restrict__ W2p,
    void* __restrict__ C0, void* __restrict__ C1, void* __restrict__ C2,
    int ops)
{
    __shared__ __align__(16) _Float16 smem[16384];   // 32 KB
    _Float16* Ah = smem;            // [128][32]
    _Float16* Al = smem + 4096;     // [128][32]
    _Float16* Bs = smem + 8192;     // [256][32]

    int wsel = blockIdx.y;
    const _Float16* W = (wsel == 0) ? W0 : (wsel == 1) ? W1 : W2p;
    void* Cc          = (wsel == 0) ? C0 : (wsel == 1) ? C1 : C2;
    int op = (ops >> (2 * wsel)) & 3;
    int row0 = blockIdx.x * 128;

    int tid = threadIdx.x;
    int lane = tid & 63;
    int wv = tid >> 6;
    int qm = (wv >> 1) * 64;
    int qn = (wv & 1) * 128;

    floatx4 acc[4][8];
    #pragma unroll
    for (int i = 0; i < 4; i++)
        #pragma unroll
        for (int j = 0; j < 8; j++)
            acc[i][j] = (floatx4){0.f, 0.f, 0.f, 0.f};

    for (int kb = 0; kb < 256; kb += 32) {
        __syncthreads();
        #pragma unroll
        for (int r = 0; r < 2; r++) {
            int q = r * 256 + tid;           // A segs: 512 of 16B per plane
            int row = q >> 2;
            int s = q & 3;
            int g = (s - row - (row >> 2)) & 3;   // bank-rotation inverse
            size_t goff = (size_t)(row0 + row) * TC + kb + g * 8;
            GLDS16(Ah_g + goff, &Ah[q * 8]);
            GLDS16(Al_g + goff, &Al[q * 8]);
        }
        #pragma unroll
        for (int r = 0; r < 4; r++) {
            int q = r * 256 + tid;           // B segs: 1024 of 16B
            int row = q >> 2, s = q & 3;
            int g = (s - row - (row >> 2)) & 3;
            GLDS16(W + (size_t)row * TC + kb + g * 8, &Bs[q * 8]);
        }
        __syncthreads();
        int sl = lane >> 4;
        half8 ah[4], al[4], b[8];
        #pragma unroll
        for (int i = 0; i < 4; i++) {
            int ra = qm + i * 16 + (lane & 15);
            int sa = (sl + ra + (ra >> 2)) & 3;
            ah[i] = *(const half8*)&Ah[ra * 32 + sa * 8];
            al[i] = *(const half8*)&Al[ra * 32 + sa * 8];
        }
        #pragma unroll
        for (int j = 0; j < 8; j++) {
            int rb = qn + j * 16 + (lane & 15);
            int sb = (sl + rb + (rb >> 2)) & 3;
            b[j] = *(const half8*)&Bs[rb * 32 + sb * 8];
        }
        #pragma unroll
        for (int i = 0; i < 4; i++)
            #pragma unroll
            for (int j = 0; j < 8; j++) {
                acc[i][j] = __builtin_amdgcn_mfma_f32_16x16x32_f16(
                    ah[i], b[j], acc[i][j], 0, 0, 0);
                acc[i][j] = __builtin_amdgcn_mfma_f32_16x16x32_f16(
                    al[i], b[j], acc[i][j], 0, 0, 0);
            }
    }

    // D mapping (16x16): row m = (lane>>4)*4 + reg, col n = lane&15
    int mr0 = (lane >> 4) * 4;
    int nc = lane & 15;
    #pragma unroll
    for (int i = 0; i < 4; i++) {
        #pragma unroll
        for (int r = 0; r < 4; r++) {
            int m = row0 + qm + i * 16 + mr0 + r;
            if (op == 0) {
                float* crow = (float*)Cc + (size_t)m * TC + qn + nc;
                #pragma unroll
                for (int j = 0; j < 8; j++)
                    crow[j * 16] = acc[i][j][r];
            } else {
                _Float16* crow = (_Float16*)Cc + (size_t)m * TC + qn + nc;
                #pragma unroll
                for (int j = 0; j < 8; j++) {
                    float vv = acc[i][j][r];
                    if (op == 1) vv = 1.f / (1.f + __expf(-vv));
                    else if (op == 2) vv = __expf(vv);
                    crow[j * 16] = (_Float16)vv;
                }
            }
        }
    }
}

// ------- WKV phase A: per-chunk local sums (ek, v f16 inputs) ----------------
__global__ __launch_bounds__(256) void wkv_chunk_sums(
    const _Float16* __restrict__ ekp, const _Float16* __restrict__ vp,
    const float* __restrict__ decay,
    float* __restrict__ SaF, float* __restrict__ SbF,
    float* __restrict__ RaB, float* __restrict__ RbB)
{
    int tid = blockIdx.x * 256 + threadIdx.x;   // B*NC2*C
    int c = tid & 255;
    int j = (tid >> 8) & (NC2 - 1);
    int b = tid >> 15;
    float w = decay[c] * (1.f / (float)TT);
    float d = __expf(-w);
    size_t base = ((size_t)(b * TT + j * CL2)) * TC + c;
    float Sa = 0.f, Sb = 0.f, Ra = 0.f, Rb = 0.f, pw = 1.f;
    #pragma unroll
    for (int i = 0; i < CL2; i++) {
        float ek = (float)ekp[base + (size_t)i * TC];
        float vv = (float)vp[base + (size_t)i * TC];
        float ekv = ek * vv;
        Sa = fmaf(d, Sa, ekv);
        Sb = fmaf(d, Sb, ek);
        Ra = fmaf(pw, ekv, Ra);
        Rb = fmaf(pw, ek, Rb);
        pw *= d;
    }
    int idx = (b * NC2 + j) * TC + c;
    SaF[idx] = Sa; SbF[idx] = Sb; RaB[idx] = Ra; RbB[idx] = Rb;
}

// ------- WKV phase B: Kogge-Stone wave scan over 128 chunks ------------------
// ONE WAVE per (b,c): 2048 waves -> 512 blocks of 256 threads.
__global__ __launch_bounds__(256) void wkv_carries(
    const float* __restrict__ SaF, const float* __restrict__ SbF,
    const float* __restrict__ RaB, const float* __restrict__ RbB,
    const float* __restrict__ decay,
    float* __restrict__ CfA, float* __restrict__ CfB,
    float* __restrict__ CbA, float* __restrict__ CbB)
{
    int gw = (blockIdx.x * 256 + threadIdx.x) >> 6;   // 0..2047
    int lane = threadIdx.x & 63;
    int c = gw & 255, b = gw >> 8;
    float w = decay[c] * (1.f / (float)TT);
    float D = __expf(-(float)CL2 * w);
    int base = b * NC2 * TC + c;
    int j0 = 2 * lane, j1 = 2 * lane + 1;
    int r0 = NC2 - 1 - j0, r1 = NC2 - 2 - j0;

    float sa0 = SaF[base + j0 * TC], sa1 = SaF[base + j1 * TC];
    float sb0 = SbF[base + j0 * TC], sb1 = SbF[base + j1 * TC];
    float qa0 = RaB[base + r0 * TC], qa1 = RaB[base + r1 * TC];
    float qb0 = RbB[base + r0 * TC], qb1 = RbB[base + r1 * TC];

    float pa = fmaf(D, sa0, sa1), pb = fmaf(D, sb0, sb1);
    float ra = fmaf(D, qa0, qa1), rb = fmaf(D, qb0, qb1);

    float dp = D * D;
    #pragma unroll
    for (int off = 1; off < 64; off <<= 1) {
        float ta = __shfl_up(pa, off, 64);
        float tb = __shfl_up(pb, off, 64);
        float ua = __shfl_up(ra, off, 64);
        float ub = __shfl_up(rb, off, 64);
        if (lane >= off) {
            pa = fmaf(dp, ta, pa); pb = fmaf(dp, tb, pb);
            ra = fmaf(dp, ua, ra); rb = fmaf(dp, ub, rb);
        }
        dp = dp * dp;
    }
    float ppa = __shfl_up(pa, 1, 64);
    float ppb = __shfl_up(pb, 1, 64);
    float pra = __shfl_up(ra, 1, 64);
    float prb = __shfl_up(rb, 1, 64);
    if (lane == 0) { ppa = 0.f; ppb = 0.f; pra = 0.f; prb = 0.f; }

    CfA[base + j0 * TC] = ppa;
    CfA[base + j1 * TC] = fmaf(D, ppa, sa0);
    CfB[base + j0 * TC] = ppb;
    CfB[base + j1 * TC] = fmaf(D, ppb, sb0);
    CbA[base + r0 * TC] = pra;
    CbA[base + r1 * TC] = fmaf(D, pra, qa0);
    CbB[base + r0 * TC] = prb;
    CbB[base + r1 * TC] = fmaf(D, prb, qb0);
}

// ------- WKV phase C: combine + gate -> Yh/Yl planes -------------------------
// Backward pass caches ek (f16) and ek*v (f32) in LDS; forward pass reads
// them back (same thread, no barrier) instead of re-reading global.
__global__ __launch_bounds__(256) void wkv_combine(
    const _Float16* __restrict__ ekp, const _Float16* __restrict__ vp,
    const _Float16* __restrict__ srp, const float* __restrict__ edgep,
    const float* __restrict__ decay, const float* __restrict__ first,
    const float* __restrict__ CfA, const float* __restrict__ CfB,
    const float* __restrict__ CbA, const float* __restrict__ CbB,
    _Float16* __restrict__ Yh, _Float16* __restrict__ Yl)
{
    __shared__ _Float16 ekL[CL2 * 256];   // 16 KB
    __shared__ float ekvL[CL2 * 256];     // 32 KB
    int bid = blockIdx.x;            // B*NC2 = 1024
    int j = bid & (NC2 - 1);
    int b = bid >> 7;
    int c = threadIdx.x;

    float w = decay[c] * (1.f / (float)TT);
    float d = __expf(-w);
    float eu = __expf(first[c] * (1.f / (float)TT));
    int cidx = (b * NC2 + j) * TC + c;
    size_t base = ((size_t)(b * TT + j * CL2)) * TC + c;

    float abArr[CL2], bbArr[CL2];
    float ab = CbA[cidx], bb = CbB[cidx];
    #pragma unroll
    for (int i = CL2 - 1; i >= 0; i--) {
        _Float16 ekh16 = ekp[base + (size_t)i * TC];
        float ek = (float)ekh16;
        float vv = (float)vp[base + (size_t)i * TC];
        float ekv = ek * vv;
        ekL[i * 256 + c] = ekh16;
        ekvL[i * 256 + c] = ekv;
        abArr[i] = ab; bbArr[i] = bb;
        ab = fmaf(d, ab, ekv);
        bb = fmaf(d, bb, ek);
    }
    float af = CfA[cidx], bf = CfB[cidx];
    #pragma unroll
    for (int i = 0; i < CL2; i++) {
        size_t idx = base + (size_t)i * TC;
        float ek = (float)ekL[i * 256 + c];
        float ekv = ekvL[i * 256 + c];
        float srv = (float)srp[idx];
        float num = fmaf(eu, ekv, af + abArr[i]);
        float den = fmaf(eu, ek, bf + bbArr[i]);
        float ev = edgep[b * TT + j * CL2 + i];
        float yv = (srv + ev) * (num / den);
        _Float16 yh = (_Float16)yv;
        _Float16 yl = (_Float16)(yv - (float)yh);
        Yh[idx] = yh;
        Yl[idx] = yl;
        af = fmaf(d, af, ekv);
        bf = fmaf(d, bf, ek);
    }
}

// -----------------------------------------------------------------------------
extern "C" void kernel_launch(void* const* d_in, const int* in_sizes, int n_in,
                              void* d_out, int out_size, void* d_ws, size_t ws_size,
                              hipStream_t stream)
{
    const float* x      = (const float*)d_in[0];
    const float* Wk     = (const float*)d_in[1];
    const float* Wv     = (const float*)d_in[2];
    const float* Wr     = (const float*)d_in[3];
    const float* Wo     = (const float*)d_in[4];
    const float* sdecay = (const float*)d_in[5];
    const float* sfirst = (const float*)d_in[6];
    float* out = (float*)d_out;

    char* ws = (char*)d_ws;
    size_t off = 0;
    const size_t PH = (size_t)TB * TT * TC * sizeof(_Float16);   // 16 MiB plane
    _Float16* Xh  = (_Float16*)(ws + off); off += PH;   // reused as Yh
    _Float16* Xl  = (_Float16*)(ws + off); off += PH;   // reused as Yl
    _Float16* ekh = (_Float16*)(ws + off); off += PH;
    _Float16* vbuf  = (_Float16*)(ws + off); off += PH;
    _Float16* srbuf = (_Float16*)(ws + off); off += PH;
    _Float16* Wf = (_Float16*)(ws + off); off += (size_t)4 * TC * TC * sizeof(_Float16);
    float* edge  = (float*)(ws + off); off += (size_t)TB * TT * sizeof(float);
    const size_t CHB = (size_t)TB * NC2 * TC * sizeof(float);    // 1 MiB each
    float* SaF = (float*)(ws + off); off += CHB;
    float* SbF = (float*)(ws + off); off += CHB;
    float* RaB = (float*)(ws + off); off += CHB;
    float* RbB = (float*)(ws + off); off += CHB;
    float* CfA = (float*)(ws + off); off += CHB;
    float* CfB = (float*)(ws + off); off += CHB;
    float* CbA = (float*)(ws + off); off += CHB;
    float* CbB = (float*)(ws + off); off += CHB;

    _Float16* WfK = Wf;
    _Float16* WfV = Wf + (size_t)TC * TC;
    _Float16* WfR = Wf + (size_t)2 * TC * TC;
    _Float16* WfO = Wf + (size_t)3 * TC * TC;

    // 1) sobel + x split + W convert
    prep<<<TB * TT + 256, 256, 0, stream>>>(x, Wk, Wv, Wr, Wo, Xh, Xl, Wf, edge);

    // 2) ek = exp(x@Wk^T) f16, v f16, sr = sigmoid(x@Wr^T) f16
    int ops1 = 2 | (3 << 2) | (1 << 4);
    gemm_split<<<dim3((TB * TT) / 128, 3), 256, 0, stream>>>(
        Xh, Xl, WfK, WfV, WfR, ekh, vbuf, srbuf, ops1);

    // 3) chunk-local sums
    wkv_chunk_sums<<<(TB * NC2 * TC) / 256, 256, 0, stream>>>(
        ekh, vbuf, sdecay, SaF, SbF, RaB, RbB);
    // 4) carries: one wave per (b,c) -> 512 blocks
    wkv_carries<<<(TB * TC * 64) / 256, 256, 0, stream>>>(
        SaF, SbF, RaB, RbB, sdecay, CfA, CfB, CbA, CbB);
    // 5) combine -> Yh/Yl (reuse Xh/Xl)
    wkv_combine<<<TB * NC2, 256, 0, stream>>>(
        ekh, vbuf, srbuf, edge, sdecay, sfirst, CfA, CfB, CbA, CbB, Xh, Xl);

    // 6) out = y @ Wo^T (fp32 out)
    gemm_split<<<dim3((TB * TT) / 128, 1), 256, 0, stream>>>(
        Xh, Xl, WfO, WfO, WfO, out, out, out, 0);
}